// Round 5
// baseline (169.528 us; speedup 1.0000x reference)
//
#include <hip/hip_runtime.h>
#include <math.h>

#define BB 16
#define TT 256
#define CC 256
#define INNER 64
#define TPR 10
#define THD 32
#define EPSV 1e-5f

typedef __attribute__((ext_vector_type(8))) short short8;
typedef __attribute__((ext_vector_type(4))) float f32x4;

__device__ __forceinline__ short f2bf(float f) {
    unsigned u = __float_as_uint(f);
    u += 0x7fffu + ((u >> 16) & 1);   // RNE
    return (short)(u >> 16);
}

// ---------------- Kernel A: y = BN(x@W1+b1); skip=y; qkv = relu(y)@Wqkv ----------------
__global__ __launch_bounds__(256) void fc1_qkv_kernel(
    const float* __restrict__ x, const float* __restrict__ W1, const float* __restrict__ b1,
    const float* __restrict__ g1, const float* __restrict__ bb1,
    const float* __restrict__ m1, const float* __restrict__ v1,
    const float* __restrict__ Wqkv,
    float* __restrict__ skip, float* __restrict__ qkv)
{
    const int ROWS = 8;
    __shared__ float xr[ROWS][CC];
    __shared__ float yr[ROWS][CC];
    const int n0 = blockIdx.x * ROWS;
    const int t = threadIdx.x;

#pragma unroll
    for (int rr = 0; rr < ROWS; ++rr)
        xr[rr][t] = x[(size_t)(n0 + rr) * CC + t];
    __syncthreads();

    float acc[ROWS];
#pragma unroll
    for (int rr = 0; rr < ROWS; ++rr) acc[rr] = 0.f;
    for (int k = 0; k < CC; ++k) {
        float wv = W1[(size_t)k * CC + t];
#pragma unroll
        for (int rr = 0; rr < ROWS; ++rr) acc[rr] = fmaf(xr[rr][k], wv, acc[rr]);
    }
    const float s1 = g1[t] * rsqrtf(v1[t] + EPSV);
    const float base = b1[t] - m1[t];
    const float bet = bb1[t];
#pragma unroll
    for (int rr = 0; rr < ROWS; ++rr) {
        float y = (acc[rr] + base) * s1 + bet;
        skip[(size_t)(n0 + rr) * CC + t] = y;
        yr[rr][t] = fmaxf(y, 0.f);
    }
    __syncthreads();

    if (t < 192) {
        float a2[ROWS];
#pragma unroll
        for (int rr = 0; rr < ROWS; ++rr) a2[rr] = 0.f;
        for (int k = 0; k < CC; ++k) {
            float wv = Wqkv[(size_t)k * 192 + t];
#pragma unroll
            for (int rr = 0; rr < ROWS; ++rr) a2[rr] = fmaf(yr[rr][k], wv, a2[rr]);
        }
#pragma unroll
        for (int rr = 0; rr < ROWS; ++rr)
            qkv[(size_t)(n0 + rr) * 192 + t] = a2[rr];
    }
}

// ---------------- Kernel B: MFMA fused vector-attention ----------------
// 1 block = 1 (b,i); 8 waves x 32 j-rows. bf16 MFMA 16x16x32 everywhere.
// LDS byte offsets:
#define O_TH   0        // 256x64 bf16 (32KB), stride 128B, swizzle mask 7. First 16KB doubles as Rl [256][32] bf16.
#define O_HID  32768    // 256x32 bf16 (16KB), stride 64B, mask 3
#define O_WA1  49152    // Wa1^T [col][k] 64x64 bf16 (8KB), stride 128B, mask 7
#define O_WA2  57344
#define O_WT2  65536    // Wt2^T [col][k] 64x32 bf16 (4KB), stride 64B, mask 3
#define O_WT1  69632    // Wt1f^T [col][k] 32x32 bf16 (2KB, K zero-padded), stride 64B, mask 3
#define O_RED  71680    // 8x2x64 f32 (4KB)
#define LDSZ   75776

__device__ __forceinline__ short8 ldfragA(const char* lds, int base, int row, int kbyte, int sl2, int mask) {
    return *(const short8*)(lds + base + (row << sl2) + (kbyte ^ ((row & mask) << 4)));
}
__device__ __forceinline__ void stbf16(char* lds, int base, int row, int col, int sl2, int mask, float v) {
    int cb = col * 2;
    int off = base + (row << sl2) + ((((cb & ~15) ^ ((row & mask) << 4))) | (cb & 15));
    *(short*)(lds + off) = f2bf(v);
}

__global__ __launch_bounds__(512) void attn_mfma_kernel(
    const float* __restrict__ r, const float* __restrict__ qkv,
    const float* __restrict__ Wt1, const float* __restrict__ bt1,
    const float* __restrict__ gt, const float* __restrict__ bbt,
    const float* __restrict__ mt, const float* __restrict__ vt,
    const float* __restrict__ Wt2, const float* __restrict__ bt2,
    const float* __restrict__ Wa1, const float* __restrict__ ba1,
    const float* __restrict__ Wa2, const float* __restrict__ ba2,
    float* __restrict__ agg)
{
    __shared__ char lds[LDSZ];
    const int n = blockIdx.x, b = n >> 8;
    const int tid = threadIdx.x;
    const int wv = tid >> 6, lane = tid & 63;
    const int lid = lane & 15, q4 = lane >> 4;
    const int kb = q4 * 16;          // k-byte offset within a 32-K row
    const int tm0 = wv * 2;          // wave's first m-tile (rows 32*wv .. +31)

    // ---- phase 0: zero Rl (16KB) + Wt1f (2KB) (zero-padded K regions must not be NaN)
    {
        uint32_t* z = (uint32_t*)lds;
#pragma unroll
        for (int e = 0; e < 8; ++e) z[tid + e * 512] = 0;
        ((uint32_t*)(lds + O_WT1))[tid] = 0;
    }
    __syncthreads();

    // ---- phase 1: stage r (bf16) + weights (bf16, transposed, swizzled)
    {
        const float* rrow = r + (size_t)n * (TT * TPR);
        for (int e = tid; e < TT * TPR; e += 512) {
            int j = e / TPR, p = e - j * TPR;
            int cb = p * 2;
            int off = (j << 6) + (((cb & ~15) ^ ((j & 3) << 4)) | (cb & 15));
            *(short*)(lds + off) = f2bf(rrow[e]);
        }
        if (tid < TPR * THD) { // 320: Wt1 folded with BN scale
            int p = tid >> 5, h = tid & 31;
            float scv = gt[h] * rsqrtf(vt[h] + EPSV);
            int cb = p * 2;
            int off = O_WT1 + (h << 6) + (((cb & ~15) ^ ((h & 3) << 4)) | (cb & 15));
            *(short*)(lds + off) = f2bf(Wt1[tid] * scv);
        }
        for (int e = tid; e < THD * INNER; e += 512) { // 2048
            int k = e >> 6, c = e & 63;
            int cb = k * 2;
            int off = O_WT2 + (c << 6) + (((cb & ~15) ^ ((c & 3) << 4)) | (cb & 15));
            *(short*)(lds + off) = f2bf(Wt2[e]);
        }
        for (int e = tid; e < INNER * INNER; e += 512) { // 4096 each
            int k = e >> 6, c = e & 63;
            int cb = k * 2;
            int sw = ((cb & ~15) ^ ((c & 7) << 4)) | (cb & 15);
            *(short*)(lds + O_WA1 + (c << 7) + sw) = f2bf(Wa1[e]);
            *(short*)(lds + O_WA2 + (c << 7) + sw) = f2bf(Wa2[e]);
        }
    }
    __syncthreads();

    // ---- GEMM1: hidden = relu(R @ Wt1f + c1)   [256,32(k,pad)]@[32,32] -> HID
    {
        short8 b1f[2];
#pragma unroll
        for (int tn = 0; tn < 2; ++tn) {
            int cr = tn * 16 + lid;
            b1f[tn] = ldfragA(lds, O_WT1, cr, kb, 6, 3);
        }
        f32x4 acc1[2][2];
#pragma unroll
        for (int tm = 0; tm < 2; ++tm) {
            int row = (tm0 + tm) * 16 + lid;
            short8 a = ldfragA(lds, 0, row, kb, 6, 3);   // Rl
#pragma unroll
            for (int tn = 0; tn < 2; ++tn) {
                f32x4 z = {0.f, 0.f, 0.f, 0.f};
                acc1[tm][tn] = __builtin_amdgcn_mfma_f32_16x16x32_bf16(a, b1f[tn], z, 0, 0, 0);
            }
        }
#pragma unroll
        for (int tn = 0; tn < 2; ++tn) {
            int col = tn * 16 + lid;
            float scv = gt[col] * rsqrtf(vt[col] + EPSV);
            float c1v = (bt1[col] - mt[col]) * scv + bbt[col];
#pragma unroll
            for (int tm = 0; tm < 2; ++tm)
#pragma unroll
                for (int g = 0; g < 4; ++g) {
                    int rw = (tm0 + tm) * 16 + q4 * 4 + g;
                    stbf16(lds, O_HID, rw, col, 6, 3, fmaxf(acc1[tm][tn][g] + c1v, 0.f));
                }
        }
    }
    // all waves must finish reading Rl before t overwrites that region
    __syncthreads();

    // ---- GEMM2: rel = hidden @ Wt2 + bt2 (kept in VGPRs); t = q - k + rel -> TH (bf16)
    f32x4 rel[2][4];
    {
        short8 b2f[4];
#pragma unroll
        for (int tn = 0; tn < 4; ++tn) {
            int cr = tn * 16 + lid;
            b2f[tn] = ldfragA(lds, O_WT2, cr, kb, 6, 3);
        }
#pragma unroll
        for (int tm = 0; tm < 2; ++tm) {
            int row = (tm0 + tm) * 16 + lid;
            short8 a = ldfragA(lds, O_HID, row, kb, 6, 3);
#pragma unroll
            for (int tn = 0; tn < 4; ++tn) {
                f32x4 z = {0.f, 0.f, 0.f, 0.f};
                rel[tm][tn] = __builtin_amdgcn_mfma_f32_16x16x32_bf16(a, b2f[tn], z, 0, 0, 0);
            }
        }
    }
    const float* kvb = qkv + (size_t)b * (TT * 192);
#pragma unroll
    for (int tn = 0; tn < 4; ++tn) {
        int col = tn * 16 + lid;
        float bt2c = bt2[col];
        float qc = qkv[(size_t)n * 192 + col];
#pragma unroll
        for (int tm = 0; tm < 2; ++tm)
#pragma unroll
            for (int g = 0; g < 4; ++g) {
                int j = (tm0 + tm) * 16 + q4 * 4 + g;
                rel[tm][tn][g] += bt2c;
                float tv = qc - kvb[j * 192 + 64 + col] + rel[tm][tn][g];
                stbf16(lds, O_TH, j, col, 7, 7, tv);
            }
    }

    // ---- GEMM3: h = relu(t @ Wa1 + ba1) -> TH (overwrite own rows)
    f32x4 acc[2][4];
#pragma unroll
    for (int tm = 0; tm < 2; ++tm)
#pragma unroll
        for (int tn = 0; tn < 4; ++tn) { f32x4 z = {0.f,0.f,0.f,0.f}; acc[tm][tn] = z; }
#pragma unroll
    for (int ks = 0; ks < 2; ++ks) {
        short8 bf[4];
#pragma unroll
        for (int tn = 0; tn < 4; ++tn) {
            int cr = tn * 16 + lid;
            bf[tn] = ldfragA(lds, O_WA1, cr, ks * 64 + kb, 7, 7);
        }
#pragma unroll
        for (int tm = 0; tm < 2; ++tm) {
            int row = (tm0 + tm) * 16 + lid;
            short8 a = ldfragA(lds, O_TH, row, ks * 64 + kb, 7, 7);
#pragma unroll
            for (int tn = 0; tn < 4; ++tn)
                acc[tm][tn] = __builtin_amdgcn_mfma_f32_16x16x32_bf16(a, bf[tn], acc[tm][tn], 0, 0, 0);
        }
    }
#pragma unroll
    for (int tn = 0; tn < 4; ++tn) {
        int col = tn * 16 + lid;
        float ba1c = ba1[col];
#pragma unroll
        for (int tm = 0; tm < 2; ++tm)
#pragma unroll
            for (int g = 0; g < 4; ++g) {
                int rw = (tm0 + tm) * 16 + q4 * 4 + g;
                stbf16(lds, O_TH, rw, col, 7, 7, fmaxf(acc[tm][tn][g] + ba1c, 0.f));
            }
    }

    // ---- GEMM4: sim = h @ Wa2 (+ba2 cancels in softmax over j)
#pragma unroll
    for (int tm = 0; tm < 2; ++tm)
#pragma unroll
        for (int tn = 0; tn < 4; ++tn) { f32x4 z = {0.f,0.f,0.f,0.f}; acc[tm][tn] = z; }
#pragma unroll
    for (int ks = 0; ks < 2; ++ks) {
        short8 bf[4];
#pragma unroll
        for (int tn = 0; tn < 4; ++tn) {
            int cr = tn * 16 + lid;
            bf[tn] = ldfragA(lds, O_WA2, cr, ks * 64 + kb, 7, 7);
        }
#pragma unroll
        for (int tm = 0; tm < 2; ++tm) {
            int row = (tm0 + tm) * 16 + lid;
            short8 a = ldfragA(lds, O_TH, row, ks * 64 + kb, 7, 7);
#pragma unroll
            for (int tn = 0; tn < 4; ++tn)
                acc[tm][tn] = __builtin_amdgcn_mfma_f32_16x16x32_bf16(a, bf[tn], acc[tm][tn], 0, 0, 0);
        }
    }

    // ---- online-free softmax over j (values tiny; no max subtraction) + weighted vv sum
    float num[4], den[4];
#pragma unroll
    for (int tn = 0; tn < 4; ++tn) { num[tn] = 0.f; den[tn] = 0.f; }
#pragma unroll
    for (int tn = 0; tn < 4; ++tn) {
        int col = tn * 16 + lid;
#pragma unroll
        for (int tm = 0; tm < 2; ++tm)
#pragma unroll
            for (int g = 0; g < 4; ++g) {
                int j = (tm0 + tm) * 16 + q4 * 4 + g;
                float ev = __expf(acc[tm][tn][g]);
                float vvv = kvb[j * 192 + 128 + col] + rel[tm][tn][g];
                den[tn] += ev;
                num[tn] = fmaf(ev, vvv, num[tn]);
            }
    }
#pragma unroll
    for (int tn = 0; tn < 4; ++tn) {
        num[tn] += __shfl_xor(num[tn], 16);
        num[tn] += __shfl_xor(num[tn], 32);
        den[tn] += __shfl_xor(den[tn], 16);
        den[tn] += __shfl_xor(den[tn], 32);
    }
    if (lane < 16) {
        float* RD = (float*)(lds + O_RED);
#pragma unroll
        for (int tn = 0; tn < 4; ++tn) {
            RD[(wv * 2 + 0) * 64 + tn * 16 + lane] = num[tn];
            RD[(wv * 2 + 1) * 64 + tn * 16 + lane] = den[tn];
        }
    }
    __syncthreads();
    if (tid < 64) {
        float* RD = (float*)(lds + O_RED);
        float nn = 0.f, dd = 0.f;
#pragma unroll
        for (int w = 0; w < 8; ++w) {
            nn += RD[(w * 2 + 0) * 64 + tid];
            dd += RD[(w * 2 + 1) * 64 + tid];
        }
        agg[(size_t)n * 64 + tid] = nn / dd;
    }
}

// ---------------- Kernel C: out = relu(BN(agg@W2+b2) + skip) ----------------
__global__ __launch_bounds__(256) void fc2_kernel(
    const float* __restrict__ agg, const float* __restrict__ W2, const float* __restrict__ b2,
    const float* __restrict__ g2, const float* __restrict__ bb2,
    const float* __restrict__ m2, const float* __restrict__ v2,
    const float* __restrict__ skip, float* __restrict__ out)
{
    const int ROWS = 8;
    __shared__ float ar[ROWS][INNER];
    const int n0 = blockIdx.x * ROWS;
    const int t = threadIdx.x;

    for (int idx = t; idx < ROWS * INNER; idx += 256)
        ((float*)ar)[idx] = agg[(size_t)n0 * INNER + idx];
    __syncthreads();

    const float s2 = g2[t] * rsqrtf(v2[t] + EPSV);
    const float base = b2[t] - m2[t];
    const float bet = bb2[t];

    float accv[ROWS];
#pragma unroll
    for (int rr = 0; rr < ROWS; ++rr) accv[rr] = 0.f;
    for (int k = 0; k < INNER; ++k) {
        float wv = W2[(size_t)k * CC + t];
#pragma unroll
        for (int rr = 0; rr < ROWS; ++rr) accv[rr] = fmaf(ar[rr][k], wv, accv[rr]);
    }
#pragma unroll
    for (int rr = 0; rr < ROWS; ++rr) {
        float y = (accv[rr] + base) * s2 + bet;
        out[(size_t)(n0 + rr) * CC + t] =
            fmaxf(y + skip[(size_t)(n0 + rr) * CC + t], 0.f);
    }
}

extern "C" void kernel_launch(void* const* d_in, const int* in_sizes, int n_in,
                              void* d_out, int out_size, void* d_ws, size_t ws_size,
                              hipStream_t stream)
{
    const float* x   = (const float*)d_in[0];
    const float* r   = (const float*)d_in[1];
    const float* W1  = (const float*)d_in[2];
    const float* b1  = (const float*)d_in[3];
    const float* g1  = (const float*)d_in[4];
    const float* bb1 = (const float*)d_in[5];
    const float* m1  = (const float*)d_in[6];
    const float* v1  = (const float*)d_in[7];
    const float* Wqkv= (const float*)d_in[8];
    const float* Wt1 = (const float*)d_in[9];
    const float* bt1 = (const float*)d_in[10];
    const float* gt  = (const float*)d_in[11];
    const float* bbt = (const float*)d_in[12];
    const float* mt  = (const float*)d_in[13];
    const float* vt  = (const float*)d_in[14];
    const float* Wt2 = (const float*)d_in[15];
    const float* bt2 = (const float*)d_in[16];
    const float* Wa1 = (const float*)d_in[17];
    const float* ba1 = (const float*)d_in[18];
    const float* Wa2 = (const float*)d_in[19];
    const float* ba2 = (const float*)d_in[20];
    const float* W2  = (const float*)d_in[21];
    const float* b2  = (const float*)d_in[22];
    const float* g2  = (const float*)d_in[23];
    const float* bb2 = (const float*)d_in[24];
    const float* m2  = (const float*)d_in[25];
    const float* v2  = (const float*)d_in[26];
    float* out = (float*)d_out;

    const int N = BB * TT;                 // 4096 rows
    float* skip = (float*)d_ws;            // N*256 floats = 4 MB
    float* qkv  = skip + (size_t)N * CC;   // N*192 floats = 3 MB
    float* agg  = qkv  + (size_t)N * 192;  // N*64  floats = 1 MB

    fc1_qkv_kernel<<<dim3(N / 8), dim3(256), 0, stream>>>(
        x, W1, b1, g1, bb1, m1, v1, Wqkv, skip, qkv);
    attn_mfma_kernel<<<dim3(N), dim3(512), 0, stream>>>(
        r, qkv, Wt1, bt1, gt, bbt, mt, vt, Wt2, bt2, Wa1, ba1, Wa2, ba2, agg);
    fc2_kernel<<<dim3(N / 8), dim3(256), 0, stream>>>(
        agg, W2, b2, g2, bb2, m2, v2, skip, out);
}

// Round 6
// 168.805 us; speedup vs baseline: 1.0043x; 1.0043x over previous
//
#include <hip/hip_runtime.h>
#include <math.h>

#define BB 16
#define TT 256
#define CC 256
#define INNER 64
#define TPR 10
#define THD 32
#define EPSV 1e-5f

typedef __attribute__((ext_vector_type(8))) short short8;
typedef __attribute__((ext_vector_type(4))) float f32x4;

__device__ __forceinline__ short f2bf(float f) {
    unsigned u = __float_as_uint(f);
    u += 0x7fffu + ((u >> 16) & 1);   // RNE
    return (short)(u >> 16);
}

// ---------------- Kernel A: y = BN(x@W1+b1); skip=y; qkv = relu(y)@Wqkv ----------------
__global__ __launch_bounds__(256) void fc1_qkv_kernel(
    const float* __restrict__ x, const float* __restrict__ W1, const float* __restrict__ b1,
    const float* __restrict__ g1, const float* __restrict__ bb1,
    const float* __restrict__ m1, const float* __restrict__ v1,
    const float* __restrict__ Wqkv,
    float* __restrict__ skip, float* __restrict__ qkv)
{
    const int ROWS = 8;
    __shared__ float xr[ROWS][CC];
    __shared__ float yr[ROWS][CC];
    const int n0 = blockIdx.x * ROWS;
    const int t = threadIdx.x;

#pragma unroll
    for (int rr = 0; rr < ROWS; ++rr)
        xr[rr][t] = x[(size_t)(n0 + rr) * CC + t];
    __syncthreads();

    float acc[ROWS];
#pragma unroll
    for (int rr = 0; rr < ROWS; ++rr) acc[rr] = 0.f;
    for (int k = 0; k < CC; ++k) {
        float wv = W1[(size_t)k * CC + t];
#pragma unroll
        for (int rr = 0; rr < ROWS; ++rr) acc[rr] = fmaf(xr[rr][k], wv, acc[rr]);
    }
    const float s1 = g1[t] * rsqrtf(v1[t] + EPSV);
    const float base = b1[t] - m1[t];
    const float bet = bb1[t];
#pragma unroll
    for (int rr = 0; rr < ROWS; ++rr) {
        float y = (acc[rr] + base) * s1 + bet;
        skip[(size_t)(n0 + rr) * CC + t] = y;
        yr[rr][t] = fmaxf(y, 0.f);
    }
    __syncthreads();

    if (t < 192) {
        float a2[ROWS];
#pragma unroll
        for (int rr = 0; rr < ROWS; ++rr) a2[rr] = 0.f;
        for (int k = 0; k < CC; ++k) {
            float wv = Wqkv[(size_t)k * 192 + t];
#pragma unroll
            for (int rr = 0; rr < ROWS; ++rr) a2[rr] = fmaf(yr[rr][k], wv, a2[rr]);
        }
#pragma unroll
        for (int rr = 0; rr < ROWS; ++rr)
            qkv[(size_t)(n0 + rr) * 192 + t] = a2[rr];
    }
}

// ---------------- Kernel B: MFMA fused vector-attention ----------------
// 1 block = 1 (b,i); 8 waves x 32 j-rows. bf16 MFMA 16x16x32 everywhere.
// LDS byte offsets:
#define O_TH   0        // 256x64 bf16 (32KB), stride 128B, swizzle mask 7. First 16KB doubles as Rl [256][32] bf16.
#define O_HID  32768    // 256x32 bf16 (16KB), stride 64B, mask 3
#define O_WA1  49152    // Wa1^T [col][k] 64x64 bf16 (8KB), stride 128B, mask 7
#define O_WA2  57344
#define O_WT2  65536    // Wt2^T [col][k] 64x32 bf16 (4KB), stride 64B, mask 3
#define O_WT1  69632    // Wt1f^T [col][k] 32x32 bf16 (2KB, K zero-padded), stride 64B, mask 3
#define O_RED  71680    // 8x2x64 f32 (4KB)
#define LDSZ   75776

__device__ __forceinline__ short8 ldfragA(const char* lds, int base, int row, int kbyte, int sl2, int mask) {
    return *(const short8*)(lds + base + (row << sl2) + (kbyte ^ ((row & mask) << 4)));
}
__device__ __forceinline__ void stbf16(char* lds, int base, int row, int col, int sl2, int mask, float v) {
    int cb = col * 2;
    int off = base + (row << sl2) + ((((cb & ~15) ^ ((row & mask) << 4))) | (cb & 15));
    *(short*)(lds + off) = f2bf(v);
}

__global__ __launch_bounds__(512) void attn_mfma_kernel(
    const float* __restrict__ r, const float* __restrict__ qkv,
    const float* __restrict__ Wt1, const float* __restrict__ bt1,
    const float* __restrict__ gt, const float* __restrict__ bbt,
    const float* __restrict__ mt, const float* __restrict__ vt,
    const float* __restrict__ Wt2, const float* __restrict__ bt2,
    const float* __restrict__ Wa1, const float* __restrict__ ba1,
    const float* __restrict__ Wa2, const float* __restrict__ ba2,
    float* __restrict__ agg)
{
    __shared__ char lds[LDSZ];
    const int n = blockIdx.x, b = n >> 8;
    const int tid = threadIdx.x;
    const int wv = tid >> 6, lane = tid & 63;
    const int lid = lane & 15, q4 = lane >> 4;
    const int kb = q4 * 16;          // k-byte offset within a 32-K row
    const int tm0 = wv * 2;          // wave's first m-tile (rows 32*wv .. +31)

    // ---- phase 0: zero Rl (16KB) + Wt1f (2KB) (zero-padded K regions must not be NaN)
    {
        uint32_t* z = (uint32_t*)lds;
#pragma unroll
        for (int e = 0; e < 8; ++e) z[tid + e * 512] = 0;
        ((uint32_t*)(lds + O_WT1))[tid] = 0;
    }
    __syncthreads();

    // ---- phase 1: stage r (bf16) + weights (bf16, transposed, swizzled)
    {
        const float* rrow = r + (size_t)n * (TT * TPR);
        for (int e = tid; e < TT * TPR; e += 512) {
            int j = e / TPR, p = e - j * TPR;
            int cb = p * 2;
            int off = (j << 6) + (((cb & ~15) ^ ((j & 3) << 4)) | (cb & 15));
            *(short*)(lds + off) = f2bf(rrow[e]);
        }
        if (tid < TPR * THD) { // 320: Wt1 folded with BN scale
            int p = tid >> 5, h = tid & 31;
            float scv = gt[h] * rsqrtf(vt[h] + EPSV);
            int cb = p * 2;
            int off = O_WT1 + (h << 6) + (((cb & ~15) ^ ((h & 3) << 4)) | (cb & 15));
            *(short*)(lds + off) = f2bf(Wt1[tid] * scv);
        }
        for (int e = tid; e < THD * INNER; e += 512) { // 2048
            int k = e >> 6, c = e & 63;
            int cb = k * 2;
            int off = O_WT2 + (c << 6) + (((cb & ~15) ^ ((c & 3) << 4)) | (cb & 15));
            *(short*)(lds + off) = f2bf(Wt2[e]);
        }
        for (int e = tid; e < INNER * INNER; e += 512) { // 4096 each
            int k = e >> 6, c = e & 63;
            int cb = k * 2;
            int sw = ((cb & ~15) ^ ((c & 7) << 4)) | (cb & 15);
            *(short*)(lds + O_WA1 + (c << 7) + sw) = f2bf(Wa1[e]);
            *(short*)(lds + O_WA2 + (c << 7) + sw) = f2bf(Wa2[e]);
        }
    }
    __syncthreads();

    // ---- GEMM1: hidden = relu(R @ Wt1f + c1)   [256,32(k,pad)]@[32,32] -> HID
    {
        short8 b1f[2];
#pragma unroll
        for (int tn = 0; tn < 2; ++tn) {
            int cr = tn * 16 + lid;
            b1f[tn] = ldfragA(lds, O_WT1, cr, kb, 6, 3);
        }
        f32x4 acc1[2][2];
#pragma unroll
        for (int tm = 0; tm < 2; ++tm) {
            int row = (tm0 + tm) * 16 + lid;
            short8 a = ldfragA(lds, 0, row, kb, 6, 3);   // Rl
#pragma unroll
            for (int tn = 0; tn < 2; ++tn) {
                f32x4 z = {0.f, 0.f, 0.f, 0.f};
                acc1[tm][tn] = __builtin_amdgcn_mfma_f32_16x16x32_bf16(a, b1f[tn], z, 0, 0, 0);
            }
        }
#pragma unroll
        for (int tn = 0; tn < 2; ++tn) {
            int col = tn * 16 + lid;
            float scv = gt[col] * rsqrtf(vt[col] + EPSV);
            float c1v = (bt1[col] - mt[col]) * scv + bbt[col];
#pragma unroll
            for (int tm = 0; tm < 2; ++tm)
#pragma unroll
                for (int g = 0; g < 4; ++g) {
                    int rw = (tm0 + tm) * 16 + q4 * 4 + g;
                    stbf16(lds, O_HID, rw, col, 6, 3, fmaxf(acc1[tm][tn][g] + c1v, 0.f));
                }
        }
    }
    // all waves must finish reading Rl before t overwrites that region
    __syncthreads();

    // ---- GEMM2: rel = hidden @ Wt2 + bt2 (kept in VGPRs); t = q - k + rel -> TH (bf16)
    f32x4 rel[2][4];
    {
        short8 b2f[4];
#pragma unroll
        for (int tn = 0; tn < 4; ++tn) {
            int cr = tn * 16 + lid;
            b2f[tn] = ldfragA(lds, O_WT2, cr, kb, 6, 3);
        }
#pragma unroll
        for (int tm = 0; tm < 2; ++tm) {
            int row = (tm0 + tm) * 16 + lid;
            short8 a = ldfragA(lds, O_HID, row, kb, 6, 3);
#pragma unroll
            for (int tn = 0; tn < 4; ++tn) {
                f32x4 z = {0.f, 0.f, 0.f, 0.f};
                rel[tm][tn] = __builtin_amdgcn_mfma_f32_16x16x32_bf16(a, b2f[tn], z, 0, 0, 0);
            }
        }
    }
    const float* kvb = qkv + (size_t)b * (TT * 192);
#pragma unroll
    for (int tn = 0; tn < 4; ++tn) {
        int col = tn * 16 + lid;
        float bt2c = bt2[col];
        float qc = qkv[(size_t)n * 192 + col];
#pragma unroll
        for (int tm = 0; tm < 2; ++tm)
#pragma unroll
            for (int g = 0; g < 4; ++g) {
                int j = (tm0 + tm) * 16 + q4 * 4 + g;
                rel[tm][tn][g] += bt2c;
                float tv = qc - kvb[j * 192 + 64 + col] + rel[tm][tn][g];
                stbf16(lds, O_TH, j, col, 7, 7, tv);
            }
    }

    // ---- GEMM3: h = relu(t @ Wa1 + ba1) -> TH (overwrite own rows)
    f32x4 acc[2][4];
#pragma unroll
    for (int tm = 0; tm < 2; ++tm)
#pragma unroll
        for (int tn = 0; tn < 4; ++tn) { f32x4 z = {0.f,0.f,0.f,0.f}; acc[tm][tn] = z; }
#pragma unroll
    for (int ks = 0; ks < 2; ++ks) {
        short8 bf[4];
#pragma unroll
        for (int tn = 0; tn < 4; ++tn) {
            int cr = tn * 16 + lid;
            bf[tn] = ldfragA(lds, O_WA1, cr, ks * 64 + kb, 7, 7);
        }
#pragma unroll
        for (int tm = 0; tm < 2; ++tm) {
            int row = (tm0 + tm) * 16 + lid;
            short8 a = ldfragA(lds, O_TH, row, ks * 64 + kb, 7, 7);
#pragma unroll
            for (int tn = 0; tn < 4; ++tn)
                acc[tm][tn] = __builtin_amdgcn_mfma_f32_16x16x32_bf16(a, bf[tn], acc[tm][tn], 0, 0, 0);
        }
    }
#pragma unroll
    for (int tn = 0; tn < 4; ++tn) {
        int col = tn * 16 + lid;
        float ba1c = ba1[col];
#pragma unroll
        for (int tm = 0; tm < 2; ++tm)
#pragma unroll
            for (int g = 0; g < 4; ++g) {
                int rw = (tm0 + tm) * 16 + q4 * 4 + g;
                stbf16(lds, O_TH, rw, col, 7, 7, fmaxf(acc[tm][tn][g] + ba1c, 0.f));
            }
    }

    // ---- GEMM4: sim = h @ Wa2 (+ba2 cancels in softmax over j)
#pragma unroll
    for (int tm = 0; tm < 2; ++tm)
#pragma unroll
        for (int tn = 0; tn < 4; ++tn) { f32x4 z = {0.f,0.f,0.f,0.f}; acc[tm][tn] = z; }
#pragma unroll
    for (int ks = 0; ks < 2; ++ks) {
        short8 bf[4];
#pragma unroll
        for (int tn = 0; tn < 4; ++tn) {
            int cr = tn * 16 + lid;
            bf[tn] = ldfragA(lds, O_WA2, cr, ks * 64 + kb, 7, 7);
        }
#pragma unroll
        for (int tm = 0; tm < 2; ++tm) {
            int row = (tm0 + tm) * 16 + lid;
            short8 a = ldfragA(lds, O_TH, row, ks * 64 + kb, 7, 7);
#pragma unroll
            for (int tn = 0; tn < 4; ++tn)
                acc[tm][tn] = __builtin_amdgcn_mfma_f32_16x16x32_bf16(a, bf[tn], acc[tm][tn], 0, 0, 0);
        }
    }

    // ---- online-free softmax over j (values tiny; no max subtraction) + weighted vv sum
    float num[4], den[4];
#pragma unroll
    for (int tn = 0; tn < 4; ++tn) { num[tn] = 0.f; den[tn] = 0.f; }
#pragma unroll
    for (int tn = 0; tn < 4; ++tn) {
        int col = tn * 16 + lid;
#pragma unroll
        for (int tm = 0; tm < 2; ++tm)
#pragma unroll
            for (int g = 0; g < 4; ++g) {
                int j = (tm0 + tm) * 16 + q4 * 4 + g;
                float ev = __expf(acc[tm][tn][g]);
                float vvv = kvb[j * 192 + 128 + col] + rel[tm][tn][g];
                den[tn] += ev;
                num[tn] = fmaf(ev, vvv, num[tn]);
            }
    }
#pragma unroll
    for (int tn = 0; tn < 4; ++tn) {
        num[tn] += __shfl_xor(num[tn], 16);
        num[tn] += __shfl_xor(num[tn], 32);
        den[tn] += __shfl_xor(den[tn], 16);
        den[tn] += __shfl_xor(den[tn], 32);
    }
    if (lane < 16) {
        float* RD = (float*)(lds + O_RED);
#pragma unroll
        for (int tn = 0; tn < 4; ++tn) {
            RD[(wv * 2 + 0) * 64 + tn * 16 + lane] = num[tn];
            RD[(wv * 2 + 1) * 64 + tn * 16 + lane] = den[tn];
        }
    }
    __syncthreads();
    if (tid < 64) {
        float* RD = (float*)(lds + O_RED);
        float nn = 0.f, dd = 0.f;
#pragma unroll
        for (int w = 0; w < 8; ++w) {
            nn += RD[(w * 2 + 0) * 64 + tid];
            dd += RD[(w * 2 + 1) * 64 + tid];
        }
        agg[(size_t)n * 64 + tid] = nn / dd;
    }
}

// ---------------- Kernel C: out = relu(BN(agg@W2+b2) + skip) ----------------
__global__ __launch_bounds__(256) void fc2_kernel(
    const float* __restrict__ agg, const float* __restrict__ W2, const float* __restrict__ b2,
    const float* __restrict__ g2, const float* __restrict__ bb2,
    const float* __restrict__ m2, const float* __restrict__ v2,
    const float* __restrict__ skip, float* __restrict__ out)
{
    const int ROWS = 8;
    __shared__ float ar[ROWS][INNER];
    const int n0 = blockIdx.x * ROWS;
    const int t = threadIdx.x;

    for (int idx = t; idx < ROWS * INNER; idx += 256)
        ((float*)ar)[idx] = agg[(size_t)n0 * INNER + idx];
    __syncthreads();

    const float s2 = g2[t] * rsqrtf(v2[t] + EPSV);
    const float base = b2[t] - m2[t];
    const float bet = bb2[t];

    float accv[ROWS];
#pragma unroll
    for (int rr = 0; rr < ROWS; ++rr) accv[rr] = 0.f;
    for (int k = 0; k < INNER; ++k) {
        float wv = W2[(size_t)k * CC + t];
#pragma unroll
        for (int rr = 0; rr < ROWS; ++rr) accv[rr] = fmaf(ar[rr][k], wv, accv[rr]);
    }
#pragma unroll
    for (int rr = 0; rr < ROWS; ++rr) {
        float y = (accv[rr] + base) * s2 + bet;
        out[(size_t)(n0 + rr) * CC + t] =
            fmaxf(y + skip[(size_t)(n0 + rr) * CC + t], 0.f);
    }
}

extern "C" void kernel_launch(void* const* d_in, const int* in_sizes, int n_in,
                              void* d_out, int out_size, void* d_ws, size_t ws_size,
                              hipStream_t stream)
{
    const float* x   = (const float*)d_in[0];
    const float* r   = (const float*)d_in[1];
    const float* W1  = (const float*)d_in[2];
    const float* b1  = (const float*)d_in[3];
    const float* g1  = (const float*)d_in[4];
    const float* bb1 = (const float*)d_in[5];
    const float* m1  = (const float*)d_in[6];
    const float* v1  = (const float*)d_in[7];
    const float* Wqkv= (const float*)d_in[8];
    const float* Wt1 = (const float*)d_in[9];
    const float* bt1 = (const float*)d_in[10];
    const float* gt  = (const float*)d_in[11];
    const float* bbt = (const float*)d_in[12];
    const float* mt  = (const float*)d_in[13];
    const float* vt  = (const float*)d_in[14];
    const float* Wt2 = (const float*)d_in[15];
    const float* bt2 = (const float*)d_in[16];
    const float* Wa1 = (const float*)d_in[17];
    const float* ba1 = (const float*)d_in[18];
    const float* Wa2 = (const float*)d_in[19];
    const float* ba2 = (const float*)d_in[20];
    const float* W2  = (const float*)d_in[21];
    const float* b2  = (const float*)d_in[22];
    const float* g2  = (const float*)d_in[23];
    const float* bb2 = (const float*)d_in[24];
    const float* m2  = (const float*)d_in[25];
    const float* v2  = (const float*)d_in[26];
    float* out = (float*)d_out;

    const int N = BB * TT;                 // 4096 rows
    float* skip = (float*)d_ws;            // N*256 floats = 4 MB
    float* qkv  = skip + (size_t)N * CC;   // N*192 floats = 3 MB
    float* agg  = qkv  + (size_t)N * 192;  // N*64  floats = 1 MB

    fc1_qkv_kernel<<<dim3(N / 8), dim3(256), 0, stream>>>(
        x, W1, b1, g1, bb1, m1, v1, Wqkv, skip, qkv);
    attn_mfma_kernel<<<dim3(N), dim3(512), 0, stream>>>(
        r, qkv, Wt1, bt1, gt, bbt, mt, vt, Wt2, bt2, Wa1, ba1, Wa2, ba2, agg);
    fc2_kernel<<<dim3(N / 8), dim3(256), 0, stream>>>(
        agg, W2, b2, g2, bb2, m2, v2, skip, out);
}